// Round 8
// baseline (225.648 us; speedup 1.0000x reference)
//
#include <hip/hip_runtime.h>
#include <stdint.h>

typedef float f32x4 __attribute__((ext_vector_type(4)));
typedef int   i32x8 __attribute__((ext_vector_type(8)));
typedef long  i64x2 __attribute__((ext_vector_type(2)));
typedef long  i64x4 __attribute__((ext_vector_type(4)));

#define VOCAB 4096
#define DIM   256
#define NROWS 65536             // 32*2048
#define SPLITS 4
#define COLS_PER (VOCAB/SPLITS) // 1024
#define CTILE 32
#define NT (COLS_PER/CTILE)     // 32 tiles
#define RPW 64                  // rows per wave: 4 row-slices of 16
#define NRS 4                   // row-slices per wave
#define WPB 4                   // waves per block
#define ROWS_PER_BLOCK (WPB*RPW)        // 256
#define NRB (NROWS/ROWS_PER_BLOCK)      // 256 row-blocks
#define WGRPS (NROWS/RPW)       // 1024 row-waves
#define SSCALE 4096.0f

#if defined(__has_builtin)
#if __has_builtin(__builtin_amdgcn_mfma_scale_f32_16x16x128_f8f6f4)
#define HAVE_MXFMA 1
#endif
#endif

// Pack 8 consecutive-k floats -> 8 fp8 bytes. A and B both use THIS helper,
// so any byte-permutation cancels in the MFMA contraction.
static __device__ __forceinline__ long pk8(float4 a, float4 b) {
    int lo = __builtin_amdgcn_cvt_pk_fp8_f32(a.x, a.y, 0, false);
    lo     = __builtin_amdgcn_cvt_pk_fp8_f32(a.z, a.w, lo, true);
    int hi = __builtin_amdgcn_cvt_pk_fp8_f32(b.x, b.y, 0, false);
    hi     = __builtin_amdgcn_cvt_pk_fp8_f32(b.z, b.w, hi, true);
    return (long)(unsigned)lo | ((long)hi << 32);
}
static __device__ __forceinline__ float4 sc4(float4 v, float s) {
    float4 r; r.x = s*v.x; r.y = s*v.y; r.z = s*v.z; r.w = s*v.w; return r;
}

// Prep: eimg = fp8(-2*S*emb) in per-lane fragment order:
// tile ct (32 cols, 8 KB): region r = sub*2+kb (2 KB), halves h (1 KB):
// byte [r*2048 + h*1024 + lane*16 + j] <-> col = sub*16 + (lane&15),
// k = kb*128 + (lane>>4)*32 + h*16 + j.   e2s[v] = sum(emb[v]^2) (loss only).
// NOTE: every 1 KB chunk is lane*16-contiguous == global_load_lds write order.
__global__ void vq_prep(const float* __restrict__ emb, uint8_t* __restrict__ eimg,
                        float* __restrict__ e2s) {
    const int t = threadIdx.x, tile = blockIdx.x;
    const int C0 = tile * CTILE;
    const int l = t & 63, q = l >> 4, n = l & 15;
    const int r = t >> 6;               // sub*2 + kb
    const int sub = r >> 1, kb = r & 1;
    const float s = -2.0f * SSCALE;
    uint8_t* tb = eimg + (size_t)tile * 8192 + r * 2048 + l * 16;
    const float* erow = emb + (size_t)(C0 + sub*16 + n) * DIM + kb*128 + q*32;
    #pragma unroll
    for (int h = 0; h < 2; ++h) {
        const float4* p = (const float4*)(erow + h*16);
        i64x2 L;
        L.x = pk8(sc4(p[0], s), sc4(p[1], s));
        L.y = pk8(sc4(p[2], s), sc4(p[3], s));
        *(i64x2*)(tb + h*1024) = L;
    }
    const int c = t >> 3, seg = t & 7;
    const float4* er = (const float4*)(emb + (size_t)(C0 + c) * DIM + seg*32);
    float ss = 0.f;
    #pragma unroll
    for (int i = 0; i < 8; ++i) {
        float4 v = er[i];
        ss += v.x*v.x + v.y*v.y + v.z*v.z + v.w*v.w;
    }
    ss += __shfl_xor(ss, 1); ss += __shfl_xor(ss, 2); ss += __shfl_xor(ss, 4);
    if (seg == 0) e2s[C0 + c] = ss;
}

// K1: 4-wave blocks share each 8 KB B tile through LDS (double-buffered,
// global_load_lds direct-to-LDS, one barrier per tile). Staging for tile t+1
// is issued BEFORE computing tile t; the barrier's vmcnt drain lands after
// ~270 cyc of MFMA+VALU >= L2 latency -> overlap enforced by barriers the
// scheduler can't undo (r6/r7 lesson: source-level reg ping-pong gets
// re-serialized by the allocator). B L2 traffic drops 4x vs per-wave loads.
// REGISTER HISTORY (do not tighten): (64,4)=128-cap spilled 186 MB (r4),
// (64,3)=168-cap spilled 107 MB (r5), 256-cap clean (r6). Working set here
// ~160 regs: (256,2) gives 256-reg budget.
__global__ __launch_bounds__(256, 2) void vq_argmin(
        const float* __restrict__ x, const uint8_t* __restrict__ eimg,
        float* __restrict__ cand, float* __restrict__ px2) {
    __shared__ __align__(16) uint8_t bsm[2][8192];
    const int tid  = threadIdx.x;
    const int lane = tid & 63;
    const int wv   = tid >> 6;
    const int quad = lane >> 4;
    const int l16  = lane & 15;
    const int split  = blockIdx.x & (SPLITS - 1); // inner: co-dispatched splits share x in L2
    const int rowgrp = blockIdx.x >> 2;           // 0..255
    const int wgrp   = rowgrp * WPB + wv;         // 0..1023
    const int waverow  = wgrp * RPW;
    const int colbase0 = split * COLS_PER;
    const uint8_t* tbase = eimg + ((size_t)(colbase0 / CTILE) << 13);

    // Stage tile ct into bsm[buf]: 8 chunks of 1 KB, 2 per wave, each one
    // global_load_lds (64 lanes x 16 B, LDS write = base + lane*16 linear).
    auto stage = [&](int buf, int ct) {
        const uint8_t* src = tbase + ((size_t)ct << 13) + (size_t)(wv * 2) * 1024 + (size_t)lane * 16;
        uint8_t* dst = &bsm[buf][(wv * 2) * 1024];
        __builtin_amdgcn_global_load_lds(
            (const __attribute__((address_space(1))) uint32_t*)src,
            (__attribute__((address_space(3))) uint32_t*)dst, 16, 0, 0);
        __builtin_amdgcn_global_load_lds(
            (const __attribute__((address_space(1))) uint32_t*)(src + 1024),
            (__attribute__((address_space(3))) uint32_t*)(dst + 1024), 16, 0, 0);
    };

    // Issue tile 0's staging first: its L2 latency hides under the A-prep.
    stage(0, 0);

    // ---- A fragments: fp8(x), 64 rows/wave = 64 VGPRs ----
    i64x4 A[NRS][2];
    float ss = 0.f;
    #pragma unroll
    for (int rs = 0; rs < NRS; ++rs) {
        const float* xrow = x + (size_t)(waverow + rs*16 + l16) * DIM + quad*32;
        #pragma unroll
        for (int kb = 0; kb < 2; ++kb) {
            const float4* p = (const float4*)(xrow + kb*128);
            i64x4 a;
            #pragma unroll
            for (int j = 0; j < 4; ++j) {
                float4 u0 = p[2*j], u1 = p[2*j+1];
                if (split == 0) {
                    ss += u0.x*u0.x + u0.y*u0.y + u0.z*u0.z + u0.w*u0.w
                        + u1.x*u1.x + u1.y*u1.y + u1.z*u1.z + u1.w*u1.w;
                }
                a[j] = pk8(u0, u1);
            }
            A[rs][kb] = a;
        }
    }
    if (split == 0) {
        #pragma unroll
        for (int off = 32; off; off >>= 1) ss += __shfl_down(ss, off);
        if (lane == 0) px2[wgrp] = ss;
    }

    float rmin[NRS][4];
    #pragma unroll
    for (int rs = 0; rs < NRS; ++rs)
        #pragma unroll
        for (int r = 0; r < 4; ++r) rmin[rs][r] = 3.402823466e+38f;

    union BU { i32x8 v; i64x4 q; struct { int4 lo, hi; } s; };

    // Full MFMA + pack/min work for one 32-col tile read from LDS.
    auto computeT = [&](int buf, int ctv) {
        const uint8_t* base = &bsm[buf][0] + (size_t)lane * 16;
        BU b[2][2];
        #pragma unroll
        for (int sub = 0; sub < 2; ++sub)
            #pragma unroll
            for (int kb = 0; kb < 2; ++kb) {
                const uint8_t* pB = base + (sub*2 + kb) * 2048;
                b[sub][kb].s.lo = *(const int4*)pB;
                b[sub][kb].s.hi = *(const int4*)(pB + 1024);
            }
        const int colbase = colbase0 + ctv * CTILE;
        #pragma unroll
        for (int sub = 0; sub < 2; ++sub) {
            f32x4 acc[NRS];
            #pragma unroll
            for (int rs = 0; rs < NRS; ++rs) acc[rs] = (f32x4){0.f,0.f,0.f,0.f};
            #pragma unroll
            for (int kb = 0; kb < 2; ++kb) {
#ifdef HAVE_MXFMA
                #pragma unroll
                for (int rs = 0; rs < NRS; ++rs)
                    acc[rs] = __builtin_amdgcn_mfma_scale_f32_16x16x128_f8f6f4(
                        __builtin_bit_cast(i32x8, A[rs][kb]), b[sub][kb].v, acc[rs],
                        0, 0, 0, 0x7F7F7F7F, 0, 0x7F7F7F7F);
#else
                #pragma unroll
                for (int rs = 0; rs < NRS; ++rs) {
                    acc[rs] = __builtin_amdgcn_mfma_f32_16x16x32_fp8_fp8(A[rs][kb].x, b[sub][kb].q.x, acc[rs], 0, 0, 0);
                    acc[rs] = __builtin_amdgcn_mfma_f32_16x16x32_fp8_fp8(A[rs][kb].y, b[sub][kb].q.y, acc[rs], 0, 0, 0);
                    acc[rs] = __builtin_amdgcn_mfma_f32_16x16x32_fp8_fp8(A[rs][kb].z, b[sub][kb].q.z, acc[rs], 0, 0, 0);
                    acc[rs] = __builtin_amdgcn_mfma_f32_16x16x32_fp8_fp8(A[rs][kb].w, b[sub][kb].q.w, acc[rs], 0, 0, 0);
                }
#endif
            }
            const unsigned colv = (unsigned)(colbase + sub*16 + l16);
            // C layout: row = quad*4 + r, col = l16. idx packed in low 12 mantissa
            // bits -> one v_and_or + one v_min_f32 carries (score, idx).
            #pragma unroll
            for (int rs = 0; rs < NRS; ++rs)
                #pragma unroll
                for (int r = 0; r < 4; ++r) {
                    unsigned pk = (__float_as_uint(acc[rs][r]) & 0xFFFFF000u) | colv;
                    rmin[rs][r] = fminf(rmin[rs][r], __uint_as_float(pk));
                }
        }
    };

    __syncthreads();                    // tile 0 staged (vmcnt drained)

    #pragma unroll 1
    for (int ct = 0; ct < NT; ++ct) {
        if (ct + 1 < NT) stage((ct + 1) & 1, ct + 1);  // issue next tile's DMA
        computeT(ct & 1, ct);                          // compute current tile
        __syncthreads();   // next tile's DMA landed; all reads of this buf done
    }

    // ---- Reduce across the 16 lanes of each quad, emit packed winner ----
    #pragma unroll
    for (int rs = 0; rs < NRS; ++rs) {
        #pragma unroll
        for (int r = 0; r < 4; ++r) {
            float v = rmin[rs][r];
            v = fminf(v, __shfl_xor(v, 8));
            v = fminf(v, __shfl_xor(v, 4));
            v = fminf(v, __shfl_xor(v, 2));
            v = fminf(v, __shfl_xor(v, 1));
            if (l16 == 0)
                cand[(size_t)split * NROWS + waverow + rs*16 + quad*4 + r] = v;
        }
    }
}

// K2: merge splits, gather emb[idx] -> out (no x read), per-block loss partial
// of (score/S + e2[idx]) = (-2 x.e + e2) per row.  64 rows per block.
__global__ __launch_bounds__(256) void vq_out(
        const float* __restrict__ emb, const float* __restrict__ e2s,
        const float* __restrict__ cand, float* __restrict__ out,
        float* __restrict__ partial) {
    __shared__ int idx_lds[64];
    const int tid = threadIdx.x;
    const int rowblock = blockIdx.x * 64;
    if (tid < 64) {
        float m = cand[rowblock + tid];
        m = fminf(m, cand[1*NROWS + rowblock + tid]);
        m = fminf(m, cand[2*NROWS + rowblock + tid]);
        m = fminf(m, cand[3*NROWS + rowblock + tid]);
        unsigned u = __float_as_uint(m);
        int idx = (int)(u & 0xFFFu);
        idx_lds[tid] = idx;
        float srow = __uint_as_float(u & 0xFFFFF000u) * (1.0f / SSCALE) + e2s[idx];
        #pragma unroll
        for (int off = 32; off; off >>= 1) srow += __shfl_down(srow, off);
        if (tid == 0) partial[blockIdx.x] = srow;
    }
    __syncthreads();

    #pragma unroll 4
    for (int it = 0; it < 16; ++it) {
        int fi  = it * 256 + tid;          // 4096 float4 per 64-row tile
        int row = fi >> 6;
        int c4  = fi & 63;
        float4 q = ((const float4*)(emb + (size_t)idx_lds[row] * DIM))[c4];
        ((float4*)(out + (size_t)(rowblock + row) * DIM))[c4] = q;
    }
}

// K3: loss = 1.25/Nel * (sum px2[1024] + sum partial[1024])
__global__ void vq_loss(const float* __restrict__ px2, const float* __restrict__ p2,
                        float* __restrict__ loss_slot) {
    __shared__ float wsum[4];
    const int tid = threadIdx.x;
    float s = 0.f;
    #pragma unroll
    for (int i = 0; i < WGRPS/256; ++i) s += px2[i * 256 + tid];
    #pragma unroll
    for (int i = 0; i < 4; ++i) s += p2[i * 256 + tid];
    #pragma unroll
    for (int off = 32; off; off >>= 1) s += __shfl_down(s, off);
    if ((tid & 63) == 0) wsum[tid >> 6] = s;
    __syncthreads();
    if (tid == 0)
        loss_slot[0] = (wsum[0] + wsum[1] + wsum[2] + wsum[3]) * (1.25f / 16777216.f);
}

extern "C" void kernel_launch(void* const* d_in, const int* in_sizes, int n_in,
                              void* d_out, int out_size, void* d_ws, size_t ws_size,
                              hipStream_t stream) {
    const float* x   = (const float*)d_in[0];   // [32,2048,256]
    const float* emb = (const float*)d_in[1];   // [4096,256]
    float* out = (float*)d_out;                 // 16777216 quantised_st + 1 loss

    uint8_t* eimg = (uint8_t*)d_ws;                                    // 1 MB
    float* e2s    = (float*)((char*)d_ws + (size_t)VOCAB*DIM);         // 16 KB
    float* cand   = (float*)((char*)e2s + VOCAB*4);                    // 1 MB
    float* px2    = (float*)((char*)cand + (size_t)SPLITS*NROWS*4);    // 4 KB
    float* p2     = (float*)((char*)px2 + WGRPS*4);                    // 4 KB
    float* loss_slot = out + (size_t)NROWS * DIM;

    vq_prep<<<VOCAB/CTILE, 256, 0, stream>>>(emb, eimg, e2s);
    vq_argmin<<<NRB*SPLITS, 64*WPB, 0, stream>>>(x, eimg, cand, px2);
    vq_out<<<NROWS/64, 256, 0, stream>>>(emb, e2s, cand, out, p2);
    vq_loss<<<1, 256, 0, stream>>>(px2, p2, loss_slot);
}

// Round 9
// 201.689 us; speedup vs baseline: 1.1188x; 1.1188x over previous
//
#include <hip/hip_runtime.h>
#include <stdint.h>

typedef float f32x4 __attribute__((ext_vector_type(4)));
typedef int   i32x8 __attribute__((ext_vector_type(8)));
typedef long  i64x2 __attribute__((ext_vector_type(2)));
typedef long  i64x4 __attribute__((ext_vector_type(4)));

#define VOCAB 4096
#define DIM   256
#define NROWS 65536             // 32*2048
#define CTILE 32
#define NT (VOCAB/CTILE)        // 128 tiles: full column sweep, NO splits
#define RPW 32                  // rows per wave: 2 row-slices of 16
#define NRS 2                   // row-slices per wave
#define WPB 4                   // waves per block
#define ROWS_PER_BLOCK (WPB*RPW)        // 128
#define NBLK (NROWS/ROWS_PER_BLOCK)     // 512 blocks = 2 per CU
#define WGRPS (NROWS/RPW)       // 2048 row-waves
#define SSCALE 4096.0f

#if defined(__has_builtin)
#if __has_builtin(__builtin_amdgcn_mfma_scale_f32_16x16x128_f8f6f4)
#define HAVE_MXFMA 1
#endif
#endif

// Pack 8 consecutive-k floats -> 8 fp8 bytes. A and B both use THIS helper,
// so any byte-permutation cancels in the MFMA contraction.
static __device__ __forceinline__ long pk8(float4 a, float4 b) {
    int lo = __builtin_amdgcn_cvt_pk_fp8_f32(a.x, a.y, 0, false);
    lo     = __builtin_amdgcn_cvt_pk_fp8_f32(a.z, a.w, lo, true);
    int hi = __builtin_amdgcn_cvt_pk_fp8_f32(b.x, b.y, 0, false);
    hi     = __builtin_amdgcn_cvt_pk_fp8_f32(b.z, b.w, hi, true);
    return (long)(unsigned)lo | ((long)hi << 32);
}
static __device__ __forceinline__ float4 sc4(float4 v, float s) {
    float4 r; r.x = s*v.x; r.y = s*v.y; r.z = s*v.z; r.w = s*v.w; return r;
}

// Prep: eimg = fp8(-2*S*emb) in per-lane fragment order:
// tile ct (32 cols, 8 KB): region r = sub*2+kb (2 KB), halves h (1 KB):
// byte [r*2048 + h*1024 + lane*16 + j] <-> col = sub*16 + (lane&15),
// k = kb*128 + (lane>>4)*32 + h*16 + j.   e2s[v] = sum(emb[v]^2) (loss only).
// NOTE: every 1 KB chunk is lane*16-contiguous == global_load_lds write order.
__global__ void vq_prep(const float* __restrict__ emb, uint8_t* __restrict__ eimg,
                        float* __restrict__ e2s) {
    const int t = threadIdx.x, tile = blockIdx.x;
    const int C0 = tile * CTILE;
    const int l = t & 63, q = l >> 4, n = l & 15;
    const int r = t >> 6;               // sub*2 + kb
    const int sub = r >> 1, kb = r & 1;
    const float s = -2.0f * SSCALE;
    uint8_t* tb = eimg + (size_t)tile * 8192 + r * 2048 + l * 16;
    const float* erow = emb + (size_t)(C0 + sub*16 + n) * DIM + kb*128 + q*32;
    #pragma unroll
    for (int h = 0; h < 2; ++h) {
        const float4* p = (const float4*)(erow + h*16);
        i64x2 L;
        L.x = pk8(sc4(p[0], s), sc4(p[1], s));
        L.y = pk8(sc4(p[2], s), sc4(p[3], s));
        *(i64x2*)(tb + h*1024) = L;
    }
    const int c = t >> 3, seg = t & 7;
    const float4* er = (const float4*)(emb + (size_t)(C0 + c) * DIM + seg*32);
    float ss = 0.f;
    #pragma unroll
    for (int i = 0; i < 8; ++i) {
        float4 v = er[i];
        ss += v.x*v.x + v.y*v.y + v.z*v.z + v.w*v.w;
    }
    ss += __shfl_xor(ss, 1); ss += __shfl_xor(ss, 2); ss += __shfl_xor(ss, 4);
    if (seg == 0) e2s[C0 + c] = ss;
}

// FUSED K1: SPLITS=1 — each 4-wave block owns 128 rows, sweeps ALL 4096 cols
// through the r8-proven LDS double-buffer (global_load_lds + 1 barrier/tile).
// x is fetched from HBM exactly ONCE (was 4x via splits); the final argmin is
// known in-block, so the epilogue gathers emb[idx] (L2-resident) and writes
// `out` directly — the separate vq_out pass (~64 MB rewrite + cand traffic)
// is eliminated. Loss partial (score/S + e2[idx] + sum x^2) folds into
// parts[wgrp].
// REGISTER HISTORY (do not tighten): (64,4)=128-cap spilled 186 MB (r4),
// (64,3)=168-cap spilled 107 MB (r5), 256-budget clean (r6/r8). Working set
// here ~110 regs: (256,2) = 256-reg budget.
__global__ __launch_bounds__(256, 2) void vq_argmin(
        const float* __restrict__ x, const uint8_t* __restrict__ eimg,
        const float* __restrict__ e2s, const float* __restrict__ emb,
        float* __restrict__ out, float* __restrict__ parts) {
    __shared__ __align__(16) uint8_t bsm[2][8192];
    __shared__ int idx_lds[ROWS_PER_BLOCK];
    const int tid  = threadIdx.x;
    const int lane = tid & 63;
    const int wv   = tid >> 6;
    const int quad = lane >> 4;
    const int l16  = lane & 15;
    const int rowblock = blockIdx.x * ROWS_PER_BLOCK;   // 0..511 * 128
    const int waverow  = rowblock + wv * RPW;
    const int wgrp     = blockIdx.x * WPB + wv;         // 0..2047

    // Stage tile ct into bsm[buf]: 8 chunks of 1 KB, 2 per wave, each one
    // global_load_lds (64 lanes x 16 B, LDS write = base + lane*16 linear).
    auto stage = [&](int buf, int ct) {
        const uint8_t* src = eimg + ((size_t)ct << 13) + (size_t)(wv * 2) * 1024 + (size_t)lane * 16;
        uint8_t* dst = &bsm[buf][(wv * 2) * 1024];
        __builtin_amdgcn_global_load_lds(
            (const __attribute__((address_space(1))) uint32_t*)src,
            (__attribute__((address_space(3))) uint32_t*)dst, 16, 0, 0);
        __builtin_amdgcn_global_load_lds(
            (const __attribute__((address_space(1))) uint32_t*)(src + 1024),
            (__attribute__((address_space(3))) uint32_t*)(dst + 1024), 16, 0, 0);
    };

    // Issue tile 0's staging first: its L2 latency hides under the A-prep.
    stage(0, 0);

    // ---- A fragments: fp8(x), 32 rows/wave = 32 VGPRs (r0-proven 8-deep
    // load batches: 8 float4 live per (rs,kb) group). ----
    i64x4 A[NRS][2];
    float ss = 0.f;
    #pragma unroll
    for (int rs = 0; rs < NRS; ++rs) {
        const float* xrow = x + (size_t)(waverow + rs*16 + l16) * DIM + quad*32;
        #pragma unroll
        for (int kb = 0; kb < 2; ++kb) {
            const float4* p = (const float4*)(xrow + kb*128);
            float4 v0=p[0],v1=p[1],v2=p[2],v3=p[3],v4=p[4],v5=p[5],v6=p[6],v7=p[7];
            ss += v0.x*v0.x+v0.y*v0.y+v0.z*v0.z+v0.w*v0.w
                + v1.x*v1.x+v1.y*v1.y+v1.z*v1.z+v1.w*v1.w
                + v2.x*v2.x+v2.y*v2.y+v2.z*v2.z+v2.w*v2.w
                + v3.x*v3.x+v3.y*v3.y+v3.z*v3.z+v3.w*v3.w
                + v4.x*v4.x+v4.y*v4.y+v4.z*v4.z+v4.w*v4.w
                + v5.x*v5.x+v5.y*v5.y+v5.z*v5.z+v5.w*v5.w
                + v6.x*v6.x+v6.y*v6.y+v6.z*v6.z+v6.w*v6.w
                + v7.x*v7.x+v7.y*v7.y+v7.z*v7.z+v7.w*v7.w;
            i64x4 a;
            a.x = pk8(v0, v1); a.y = pk8(v2, v3);
            a.z = pk8(v4, v5); a.w = pk8(v6, v7);
            A[rs][kb] = a;
        }
    }
    // ss: full-wave sum of x^2 over this wave's 32 rows -> lane 0.
    #pragma unroll
    for (int off = 32; off; off >>= 1) ss += __shfl_down(ss, off);

    float rmin[NRS][4];
    #pragma unroll
    for (int rs = 0; rs < NRS; ++rs)
        #pragma unroll
        for (int r = 0; r < 4; ++r) rmin[rs][r] = 3.402823466e+38f;

    union BU { i32x8 v; i64x4 q; struct { int4 lo, hi; } s; };

    // Full MFMA + pack/min work for one 32-col tile read from LDS.
    auto computeT = [&](int buf, int ctv) {
        const uint8_t* base = &bsm[buf][0] + (size_t)lane * 16;
        BU b[2][2];
        #pragma unroll
        for (int sub = 0; sub < 2; ++sub)
            #pragma unroll
            for (int kb = 0; kb < 2; ++kb) {
                const uint8_t* pB = base + (sub*2 + kb) * 2048;
                b[sub][kb].s.lo = *(const int4*)pB;
                b[sub][kb].s.hi = *(const int4*)(pB + 1024);
            }
        const int colbase = ctv * CTILE;
        #pragma unroll
        for (int sub = 0; sub < 2; ++sub) {
            f32x4 acc[NRS];
            #pragma unroll
            for (int rs = 0; rs < NRS; ++rs) acc[rs] = (f32x4){0.f,0.f,0.f,0.f};
            #pragma unroll
            for (int kb = 0; kb < 2; ++kb) {
#ifdef HAVE_MXFMA
                #pragma unroll
                for (int rs = 0; rs < NRS; ++rs)
                    acc[rs] = __builtin_amdgcn_mfma_scale_f32_16x16x128_f8f6f4(
                        __builtin_bit_cast(i32x8, A[rs][kb]), b[sub][kb].v, acc[rs],
                        0, 0, 0, 0x7F7F7F7F, 0, 0x7F7F7F7F);
#else
                #pragma unroll
                for (int rs = 0; rs < NRS; ++rs) {
                    acc[rs] = __builtin_amdgcn_mfma_f32_16x16x32_fp8_fp8(A[rs][kb].x, b[sub][kb].q.x, acc[rs], 0, 0, 0);
                    acc[rs] = __builtin_amdgcn_mfma_f32_16x16x32_fp8_fp8(A[rs][kb].y, b[sub][kb].q.y, acc[rs], 0, 0, 0);
                    acc[rs] = __builtin_amdgcn_mfma_f32_16x16x32_fp8_fp8(A[rs][kb].z, b[sub][kb].q.z, acc[rs], 0, 0, 0);
                    acc[rs] = __builtin_amdgcn_mfma_f32_16x16x32_fp8_fp8(A[rs][kb].w, b[sub][kb].q.w, acc[rs], 0, 0, 0);
                }
#endif
            }
            const unsigned colv = (unsigned)(colbase + sub*16 + l16);
            // C layout: row = quad*4 + r, col = l16. idx packed in low 12 mantissa
            // bits -> one v_and_or + one v_min_f32 carries (score, idx).
            #pragma unroll
            for (int rs = 0; rs < NRS; ++rs)
                #pragma unroll
                for (int r = 0; r < 4; ++r) {
                    unsigned pk = (__float_as_uint(acc[rs][r]) & 0xFFFFF000u) | colv;
                    rmin[rs][r] = fminf(rmin[rs][r], __uint_as_float(pk));
                }
        }
    };

    __syncthreads();                    // tile 0 staged (vmcnt drained)

    #pragma unroll 1
    for (int ct = 0; ct < NT; ++ct) {
        if (ct + 1 < NT) stage((ct + 1) & 1, ct + 1);  // issue next tile's DMA
        computeT(ct & 1, ct);                          // compute current tile
        __syncthreads();   // next tile's DMA landed; all reads of this buf done
    }

    // ---- Winners: 16-lane reduce, record idx + loss contribution ----
    float lsum = 0.f;
    #pragma unroll
    for (int rs = 0; rs < NRS; ++rs) {
        #pragma unroll
        for (int r = 0; r < 4; ++r) {
            float v = rmin[rs][r];
            v = fminf(v, __shfl_xor(v, 8));
            v = fminf(v, __shfl_xor(v, 4));
            v = fminf(v, __shfl_xor(v, 2));
            v = fminf(v, __shfl_xor(v, 1));
            if (l16 == 0) {
                unsigned u = __float_as_uint(v);
                int idx = (int)(u & 0xFFFu);
                idx_lds[wv*RPW + rs*16 + quad*4 + r] = idx;
                lsum += __uint_as_float(u & 0xFFFFF000u) * (1.0f / SSCALE) + e2s[idx];
            }
        }
    }
    // lsum lives in lanes 0,16,32,48 -> lane 0; combine with ss.
    lsum += __shfl_down(lsum, 32);
    lsum += __shfl_down(lsum, 16);
    if (lane == 0) parts[wgrp] = ss + lsum;

    __syncthreads();                    // idx_lds visible to all waves

    // ---- Gather emb[idx] -> out: 128 rows x 64 float4, 32 per thread.
    // Each wave handles one row per iter: uniform idx -> coalesced 1 KB read
    // from L2-resident emb, coalesced 1 KB write to out.
    #pragma unroll 4
    for (int it = 0; it < 32; ++it) {
        int fi  = it * 256 + tid;
        int row = fi >> 6;
        int c4  = fi & 63;
        float4 q = ((const float4*)(emb + (size_t)idx_lds[row] * DIM))[c4];
        ((float4*)(out + (size_t)(rowblock + row) * DIM))[c4] = q;
    }
}

// K3: loss = 1.25/Nel * sum parts[2048]
__global__ void vq_loss(const float* __restrict__ parts,
                        float* __restrict__ loss_slot) {
    __shared__ float wsum[4];
    const int tid = threadIdx.x;
    float s = 0.f;
    #pragma unroll
    for (int i = 0; i < WGRPS/256; ++i) s += parts[i * 256 + tid];
    #pragma unroll
    for (int off = 32; off; off >>= 1) s += __shfl_down(s, off);
    if ((tid & 63) == 0) wsum[tid >> 6] = s;
    __syncthreads();
    if (tid == 0)
        loss_slot[0] = (wsum[0] + wsum[1] + wsum[2] + wsum[3]) * (1.25f / 16777216.f);
}

extern "C" void kernel_launch(void* const* d_in, const int* in_sizes, int n_in,
                              void* d_out, int out_size, void* d_ws, size_t ws_size,
                              hipStream_t stream) {
    const float* x   = (const float*)d_in[0];   // [32,2048,256]
    const float* emb = (const float*)d_in[1];   // [4096,256]
    float* out = (float*)d_out;                 // 16777216 quantised_st + 1 loss

    uint8_t* eimg = (uint8_t*)d_ws;                                    // 1 MB
    float* e2s    = (float*)((char*)d_ws + (size_t)VOCAB*DIM);         // 16 KB
    float* parts  = (float*)((char*)e2s + VOCAB*4);                    // 8 KB
    float* loss_slot = out + (size_t)NROWS * DIM;

    vq_prep<<<VOCAB/CTILE, 256, 0, stream>>>(emb, eimg, e2s);
    vq_argmin<<<NBLK, 64*WPB, 0, stream>>>(x, eimg, e2s, emb, out, parts);
    vq_loss<<<1, 256, 0, stream>>>(parts, loss_slot);
}

// Round 10
// 188.175 us; speedup vs baseline: 1.1991x; 1.0718x over previous
//
#include <hip/hip_runtime.h>
#include <stdint.h>

typedef float f32x4 __attribute__((ext_vector_type(4)));
typedef int   i32x8 __attribute__((ext_vector_type(8)));
typedef long  i64x2 __attribute__((ext_vector_type(2)));
typedef long  i64x4 __attribute__((ext_vector_type(4)));

#define VOCAB 4096
#define DIM   256
#define NROWS 65536             // 32*2048
#define CTILE 32
#define NT (VOCAB/CTILE)        // 128 tiles: full column sweep, NO splits
#define RPW 32                  // rows per wave: 2 row-slices of 16
#define NRS 2                   // row-slices per wave
#define WPB 4                   // waves per block
#define ROWS_PER_BLOCK (WPB*RPW)        // 128
#define NBLK (NROWS/ROWS_PER_BLOCK)     // 512 blocks = 2 per CU
#define WGRPS (NROWS/RPW)       // 2048 row-waves
#define SSCALE 4096.0f

#if defined(__has_builtin)
#if __has_builtin(__builtin_amdgcn_mfma_scale_f32_16x16x128_f8f6f4)
#define HAVE_MXFMA 1
#endif
#endif

// Pack 8 consecutive-k floats -> 8 fp8 bytes. A and B both use THIS helper,
// so any byte-permutation cancels in the MFMA contraction.
static __device__ __forceinline__ long pk8(float4 a, float4 b) {
    int lo = __builtin_amdgcn_cvt_pk_fp8_f32(a.x, a.y, 0, false);
    lo     = __builtin_amdgcn_cvt_pk_fp8_f32(a.z, a.w, lo, true);
    int hi = __builtin_amdgcn_cvt_pk_fp8_f32(b.x, b.y, 0, false);
    hi     = __builtin_amdgcn_cvt_pk_fp8_f32(b.z, b.w, hi, true);
    return (long)(unsigned)lo | ((long)hi << 32);
}
static __device__ __forceinline__ float4 sc4(float4 v, float s) {
    float4 r; r.x = s*v.x; r.y = s*v.y; r.z = s*v.z; r.w = s*v.w; return r;
}

// Prep: eimg = fp8(-2*S*emb) in per-lane fragment order:
// tile ct (32 cols, 8 KB): region r = sub*2+kb (2 KB), halves h (1 KB):
// byte [r*2048 + h*1024 + lane*16 + j] <-> col = sub*16 + (lane&15),
// k = kb*128 + (lane>>4)*32 + h*16 + j.   e2s[v] = sum(emb[v]^2) (loss only).
// NOTE: every 1 KB chunk is lane*16-contiguous == global_load_lds write order.
__global__ void vq_prep(const float* __restrict__ emb, uint8_t* __restrict__ eimg,
                        float* __restrict__ e2s) {
    const int t = threadIdx.x, tile = blockIdx.x;
    const int C0 = tile * CTILE;
    const int l = t & 63, q = l >> 4, n = l & 15;
    const int r = t >> 6;               // sub*2 + kb
    const int sub = r >> 1, kb = r & 1;
    const float s = -2.0f * SSCALE;
    uint8_t* tb = eimg + (size_t)tile * 8192 + r * 2048 + l * 16;
    const float* erow = emb + (size_t)(C0 + sub*16 + n) * DIM + kb*128 + q*32;
    #pragma unroll
    for (int h = 0; h < 2; ++h) {
        const float4* p = (const float4*)(erow + h*16);
        i64x2 L;
        L.x = pk8(sc4(p[0], s), sc4(p[1], s));
        L.y = pk8(sc4(p[2], s), sc4(p[3], s));
        *(i64x2*)(tb + h*1024) = L;
    }
    const int c = t >> 3, seg = t & 7;
    const float4* er = (const float4*)(emb + (size_t)(C0 + c) * DIM + seg*32);
    float ss = 0.f;
    #pragma unroll
    for (int i = 0; i < 8; ++i) {
        float4 v = er[i];
        ss += v.x*v.x + v.y*v.y + v.z*v.z + v.w*v.w;
    }
    ss += __shfl_xor(ss, 1); ss += __shfl_xor(ss, 2); ss += __shfl_xor(ss, 4);
    if (seg == 0) e2s[C0 + c] = ss;
}

// FUSED K1: each 4-wave block owns 128 rows, sweeps all 4096 cols.
// r9 LESSON (the ~120us invariant): __syncthreads() drains vmcnt(0), so the
// staging DMA's L2 latency beyond one compute-phase is EXPOSED at each of the
// 128 barriers (~500+ cyc/tile). Fix = guide's T3+T4: 3-buffer ring, stage
// t+2 during t (depth-2 prefetch), and a COUNTED `s_waitcnt vmcnt(2)` + raw
// s_barrier: only t+1's DMA (issued a full phase ago) must have landed; t+2's
// stays in flight across the barrier. vmcnt retires in order -> prologue
// A-loads implicitly covered. Buffer reuse (stage t+2 overwrites buf (t-1)%3)
// is safe: all reads of that buf finished before the t-1 barrier.
// Tile-start STAGGER decorrelates 512 blocks hitting the same 8KB eimg tile.
// REGISTER HISTORY (do not tighten): (64,4)=128-cap spilled 186 MB (r4),
// (64,3)=168-cap spilled 107 MB (r5), 256-budget clean (r6/r8/r9: VGPR=52).
__global__ __launch_bounds__(256, 2) void vq_argmin(
        const float* __restrict__ x, const uint8_t* __restrict__ eimg,
        const float* __restrict__ e2s, const float* __restrict__ emb,
        float* __restrict__ out, float* __restrict__ parts) {
    __shared__ __align__(16) uint8_t bsm[3][8192];
    __shared__ int idx_lds[ROWS_PER_BLOCK];
    const int tid  = threadIdx.x;
    const int lane = tid & 63;
    const int wv   = tid >> 6;
    const int quad = lane >> 4;
    const int l16  = lane & 15;
    const int rowblock = blockIdx.x * ROWS_PER_BLOCK;   // 0..511 * 128
    const int waverow  = rowblock + wv * RPW;
    const int wgrp     = blockIdx.x * WPB + wv;         // 0..2047
    const int ctstart  = blockIdx.x & (NT - 1);         // stagger the sweep

    // Stage tile ct into bsm[buf]: 8 chunks of 1 KB, 2 per wave, each one
    // global_load_lds (64 lanes x 16 B, LDS write = base + lane*16 linear).
    auto stage = [&](int buf, int ct) {
        const uint8_t* src = eimg + ((size_t)ct << 13) + (size_t)(wv * 2) * 1024 + (size_t)lane * 16;
        uint8_t* dst = &bsm[buf][(wv * 2) * 1024];
        __builtin_amdgcn_global_load_lds(
            (const __attribute__((address_space(1))) uint32_t*)src,
            (__attribute__((address_space(3))) uint32_t*)dst, 16, 0, 0);
        __builtin_amdgcn_global_load_lds(
            (const __attribute__((address_space(1))) uint32_t*)(src + 1024),
            (__attribute__((address_space(3))) uint32_t*)(dst + 1024), 16, 0, 0);
    };

    // Prologue: stage tiles 0 and 1; their latency hides under the A-prep.
    stage(0, ctstart);
    stage(1, (ctstart + 1) & (NT - 1));

    // ---- A fragments: fp8(x), 32 rows/wave = 32 VGPRs (r0-proven 8-deep
    // load batches). These loads are ISSUED AFTER the stage DMAs; consuming
    // them forces (in-order vmcnt) the stage DMAs to have retired too.
    i64x4 A[NRS][2];
    float ss = 0.f;
    #pragma unroll
    for (int rs = 0; rs < NRS; ++rs) {
        const float* xrow = x + (size_t)(waverow + rs*16 + l16) * DIM + quad*32;
        #pragma unroll
        for (int kb = 0; kb < 2; ++kb) {
            const float4* p = (const float4*)(xrow + kb*128);
            float4 v0=p[0],v1=p[1],v2=p[2],v3=p[3],v4=p[4],v5=p[5],v6=p[6],v7=p[7];
            ss += v0.x*v0.x+v0.y*v0.y+v0.z*v0.z+v0.w*v0.w
                + v1.x*v1.x+v1.y*v1.y+v1.z*v1.z+v1.w*v1.w
                + v2.x*v2.x+v2.y*v2.y+v2.z*v2.z+v2.w*v2.w
                + v3.x*v3.x+v3.y*v3.y+v3.z*v3.z+v3.w*v3.w
                + v4.x*v4.x+v4.y*v4.y+v4.z*v4.z+v4.w*v4.w
                + v5.x*v5.x+v5.y*v5.y+v5.z*v5.z+v5.w*v5.w
                + v6.x*v6.x+v6.y*v6.y+v6.z*v6.z+v6.w*v6.w
                + v7.x*v7.x+v7.y*v7.y+v7.z*v7.z+v7.w*v7.w;
            i64x4 a;
            a.x = pk8(v0, v1); a.y = pk8(v2, v3);
            a.z = pk8(v4, v5); a.w = pk8(v6, v7);
            A[rs][kb] = a;
        }
    }
    // ss: full-wave sum of x^2 over this wave's 32 rows -> lane 0.
    #pragma unroll
    for (int off = 32; off; off >>= 1) ss += __shfl_down(ss, off);

    float rmin[NRS][4];
    #pragma unroll
    for (int rs = 0; rs < NRS; ++rs)
        #pragma unroll
        for (int r = 0; r < 4; ++r) rmin[rs][r] = 3.402823466e+38f;

    union BU { i32x8 v; i64x4 q; struct { int4 lo, hi; } s; };

    // Full MFMA + pack/min work for one 32-col tile read from LDS.
    auto computeT = [&](int buf, int ctv) {
        const uint8_t* base = &bsm[buf][0] + (size_t)lane * 16;
        BU b[2][2];
        #pragma unroll
        for (int sub = 0; sub < 2; ++sub)
            #pragma unroll
            for (int kb = 0; kb < 2; ++kb) {
                const uint8_t* pB = base + (sub*2 + kb) * 2048;
                b[sub][kb].s.lo = *(const int4*)pB;
                b[sub][kb].s.hi = *(const int4*)(pB + 1024);
            }
        const int colbase = ctv * CTILE;
        #pragma unroll
        for (int sub = 0; sub < 2; ++sub) {
            f32x4 acc[NRS];
            #pragma unroll
            for (int rs = 0; rs < NRS; ++rs) acc[rs] = (f32x4){0.f,0.f,0.f,0.f};
            #pragma unroll
            for (int kb = 0; kb < 2; ++kb) {
#ifdef HAVE_MXFMA
                #pragma unroll
                for (int rs = 0; rs < NRS; ++rs)
                    acc[rs] = __builtin_amdgcn_mfma_scale_f32_16x16x128_f8f6f4(
                        __builtin_bit_cast(i32x8, A[rs][kb]), b[sub][kb].v, acc[rs],
                        0, 0, 0, 0x7F7F7F7F, 0, 0x7F7F7F7F);
#else
                #pragma unroll
                for (int rs = 0; rs < NRS; ++rs) {
                    acc[rs] = __builtin_amdgcn_mfma_f32_16x16x32_fp8_fp8(A[rs][kb].x, b[sub][kb].q.x, acc[rs], 0, 0, 0);
                    acc[rs] = __builtin_amdgcn_mfma_f32_16x16x32_fp8_fp8(A[rs][kb].y, b[sub][kb].q.y, acc[rs], 0, 0, 0);
                    acc[rs] = __builtin_amdgcn_mfma_f32_16x16x32_fp8_fp8(A[rs][kb].z, b[sub][kb].q.z, acc[rs], 0, 0, 0);
                    acc[rs] = __builtin_amdgcn_mfma_f32_16x16x32_fp8_fp8(A[rs][kb].w, b[sub][kb].q.w, acc[rs], 0, 0, 0);
                }
#endif
            }
            const unsigned colv = (unsigned)(colbase + sub*16 + l16);
            // C layout: row = quad*4 + r, col = l16. idx packed in low 12 mantissa
            // bits -> one v_and_or + one v_min_f32 carries (score, idx).
            #pragma unroll
            for (int rs = 0; rs < NRS; ++rs)
                #pragma unroll
                for (int r = 0; r < 4; ++r) {
                    unsigned pk = (__float_as_uint(acc[rs][r]) & 0xFFFFF000u) | colv;
                    rmin[rs][r] = fminf(rmin[rs][r], __uint_as_float(pk));
                }
        }
    };

    __syncthreads();            // prologue: tiles 0,1 staged (full drain, once)

    #pragma unroll 1
    for (int t = 0; t < NT; ++t) {
        if (t + 2 < NT) stage((t + 2) % 3, (ctstart + t + 2) & (NT - 1));
        computeT(t % 3, (ctstart + t) & (NT - 1));
        // Counted wait: require tile t+1's DMA (issued at t-1) landed; allow
        // tile t+2's 2 loads to stay in flight across the raw barrier.
        if (t + 2 < NT) {
            asm volatile("s_waitcnt vmcnt(2)" ::: "memory");
        } else {
            asm volatile("s_waitcnt vmcnt(0)" ::: "memory");
        }
        __builtin_amdgcn_s_barrier();
    }

    // ---- Winners: 16-lane reduce, record idx + loss contribution ----
    float lsum = 0.f;
    #pragma unroll
    for (int rs = 0; rs < NRS; ++rs) {
        #pragma unroll
        for (int r = 0; r < 4; ++r) {
            float v = rmin[rs][r];
            v = fminf(v, __shfl_xor(v, 8));
            v = fminf(v, __shfl_xor(v, 4));
            v = fminf(v, __shfl_xor(v, 2));
            v = fminf(v, __shfl_xor(v, 1));
            if (l16 == 0) {
                unsigned u = __float_as_uint(v);
                int idx = (int)(u & 0xFFFu);
                idx_lds[wv*RPW + rs*16 + quad*4 + r] = idx;
                lsum += __uint_as_float(u & 0xFFFFF000u) * (1.0f / SSCALE) + e2s[idx];
            }
        }
    }
    // lsum lives in lanes 0,16,32,48 -> lane 0; combine with ss.
    lsum += __shfl_down(lsum, 32);
    lsum += __shfl_down(lsum, 16);
    if (lane == 0) parts[wgrp] = ss + lsum;

    __syncthreads();                    // idx_lds visible to all waves

    // ---- Gather emb[idx] -> out: 128 rows x 64 float4, 32 per thread.
    // Each wave handles one row per iter: uniform idx -> coalesced 1 KB read
    // from L2-resident emb, coalesced 1 KB write to out.
    #pragma unroll 4
    for (int it = 0; it < 32; ++it) {
        int fi  = it * 256 + tid;
        int row = fi >> 6;
        int c4  = fi & 63;
        float4 q = ((const float4*)(emb + (size_t)idx_lds[row] * DIM))[c4];
        ((float4*)(out + (size_t)(rowblock + row) * DIM))[c4] = q;
    }
}

// K3: loss = 1.25/Nel * sum parts[2048]
__global__ void vq_loss(const float* __restrict__ parts,
                        float* __restrict__ loss_slot) {
    __shared__ float wsum[4];
    const int tid = threadIdx.x;
    float s = 0.f;
    #pragma unroll
    for (int i = 0; i < WGRPS/256; ++i) s += parts[i * 256 + tid];
    #pragma unroll
    for (int off = 32; off; off >>= 1) s += __shfl_down(s, off);
    if ((tid & 63) == 0) wsum[tid >> 6] = s;
    __syncthreads();
    if (tid == 0)
        loss_slot[0] = (wsum[0] + wsum[1] + wsum[2] + wsum[3]) * (1.25f / 16777216.f);
}

extern "C" void kernel_launch(void* const* d_in, const int* in_sizes, int n_in,
                              void* d_out, int out_size, void* d_ws, size_t ws_size,
                              hipStream_t stream) {
    const float* x   = (const float*)d_in[0];   // [32,2048,256]
    const float* emb = (const float*)d_in[1];   // [4096,256]
    float* out = (float*)d_out;                 // 16777216 quantised_st + 1 loss

    uint8_t* eimg = (uint8_t*)d_ws;                                    // 1 MB
    float* e2s    = (float*)((char*)d_ws + (size_t)VOCAB*DIM);         // 16 KB
    float* parts  = (float*)((char*)e2s + VOCAB*4);                    // 8 KB
    float* loss_slot = out + (size_t)NROWS * DIM;

    vq_prep<<<VOCAB/CTILE, 256, 0, stream>>>(emb, eimg, e2s);
    vq_argmin<<<NBLK, 64*WPB, 0, stream>>>(x, eimg, e2s, emb, out, parts);
    vq_loss<<<1, 256, 0, stream>>>(parts, loss_slot);
}

// Round 11
// 177.322 us; speedup vs baseline: 1.2725x; 1.0612x over previous
//
#include <hip/hip_runtime.h>
#include <stdint.h>

typedef float f32x4 __attribute__((ext_vector_type(4)));
typedef int   i32x8 __attribute__((ext_vector_type(8)));
typedef long  i64x2 __attribute__((ext_vector_type(2)));
typedef long  i64x4 __attribute__((ext_vector_type(4)));

#define VOCAB 4096
#define DIM   256
#define NROWS 65536             // 32*2048
#define CTILE 32
#define NT (VOCAB/CTILE)        // 128 col-tiles
#define NPAIR (NT/2)            // 64 pair-rounds (2 tiles per barrier round)
#define RPW 32                  // rows per wave: 2 row-slices of 16
#define NRS 2                   // row-slices per wave
#define WPB 4                   // waves per block
#define ROWS_PER_BLOCK (WPB*RPW)        // 128
#define NBLK (NROWS/ROWS_PER_BLOCK)     // 512 blocks = 2 per CU
#define WGRPS (NROWS/RPW)       // 2048 row-waves
#define SSCALE 4096.0f

#if defined(__has_builtin)
#if __has_builtin(__builtin_amdgcn_mfma_scale_f32_16x16x128_f8f6f4)
#define HAVE_MXFMA 1
#endif
#endif

// Pack 8 consecutive-k floats -> 8 fp8 bytes. A and B both use THIS helper,
// so any byte-permutation cancels in the MFMA contraction.
static __device__ __forceinline__ long pk8(float4 a, float4 b) {
    int lo = __builtin_amdgcn_cvt_pk_fp8_f32(a.x, a.y, 0, false);
    lo     = __builtin_amdgcn_cvt_pk_fp8_f32(a.z, a.w, lo, true);
    int hi = __builtin_amdgcn_cvt_pk_fp8_f32(b.x, b.y, 0, false);
    hi     = __builtin_amdgcn_cvt_pk_fp8_f32(b.z, b.w, hi, true);
    return (long)(unsigned)lo | ((long)hi << 32);
}
static __device__ __forceinline__ float4 sc4(float4 v, float s) {
    float4 r; r.x = s*v.x; r.y = s*v.y; r.z = s*v.z; r.w = s*v.w; return r;
}

// Prep: eimg = fp8(-2*S*emb) in per-lane fragment order:
// tile ct (32 cols, 8 KB): region r = sub*2+kb (2 KB), halves h (1 KB):
// byte [r*2048 + h*1024 + lane*16 + j] <-> col = sub*16 + (lane&15),
// k = kb*128 + (lane>>4)*32 + h*16 + j.   e2s[v] = sum(emb[v]^2) (loss only).
// NOTE: every 1 KB chunk is lane*16-contiguous == global_load_lds write order.
__global__ void vq_prep(const float* __restrict__ emb, uint8_t* __restrict__ eimg,
                        float* __restrict__ e2s) {
    const int t = threadIdx.x, tile = blockIdx.x;
    const int C0 = tile * CTILE;
    const int l = t & 63, q = l >> 4, n = l & 15;
    const int r = t >> 6;               // sub*2 + kb
    const int sub = r >> 1, kb = r & 1;
    const float s = -2.0f * SSCALE;
    uint8_t* tb = eimg + (size_t)tile * 8192 + r * 2048 + l * 16;
    const float* erow = emb + (size_t)(C0 + sub*16 + n) * DIM + kb*128 + q*32;
    #pragma unroll
    for (int h = 0; h < 2; ++h) {
        const float4* p = (const float4*)(erow + h*16);
        i64x2 L;
        L.x = pk8(sc4(p[0], s), sc4(p[1], s));
        L.y = pk8(sc4(p[2], s), sc4(p[3], s));
        *(i64x2*)(tb + h*1024) = L;
    }
    const int c = t >> 3, seg = t & 7;
    const float4* er = (const float4*)(emb + (size_t)(C0 + c) * DIM + seg*32);
    float ss = 0.f;
    #pragma unroll
    for (int i = 0; i < 8; ++i) {
        float4 v = er[i];
        ss += v.x*v.x + v.y*v.y + v.z*v.z + v.w*v.w;
    }
    ss += __shfl_xor(ss, 1); ss += __shfl_xor(ss, 2); ss += __shfl_xor(ss, 4);
    if (seg == 0) e2s[C0 + c] = ss;
}

// FUSED K1: each 4-wave block owns 128 rows, sweeps all 4096 cols.
// Schedule (r10+): 3-buffer ring of 16 KB PAIR-tiles (2 col-tiles per barrier
// round, 64 rounds): halves the per-round overhead count vs r10's 128 rounds.
// Counted vmcnt(4) + raw s_barrier keeps pair t+2's 4 DMAs in flight across
// the barrier (r10-verified counted-wait pattern). T5 s_setprio(1) brackets
// each MFMA cluster: 2 independent staggered blocks/CU = phase role-diversity,
// the regime where setprio measurably pays.
// REGISTER HISTORY (do not tighten): (64,4)=128-cap spilled 186 MB (r4),
// (64,3)=168-cap spilled 107 MB (r5), 256-budget clean (r6/r8/r9/r10).
__global__ __launch_bounds__(256, 2) void vq_argmin(
        const float* __restrict__ x, const uint8_t* __restrict__ eimg,
        const float* __restrict__ e2s, const float* __restrict__ emb,
        float* __restrict__ out, float* __restrict__ parts) {
    __shared__ __align__(16) uint8_t bsm[3][16384];
    __shared__ int idx_lds[ROWS_PER_BLOCK];
    const int tid  = threadIdx.x;
    const int lane = tid & 63;
    const int wv   = tid >> 6;
    const int quad = lane >> 4;
    const int l16  = lane & 15;
    const int rowblock = blockIdx.x * ROWS_PER_BLOCK;   // 0..511 * 128
    const int waverow  = rowblock + wv * RPW;
    const int wgrp     = blockIdx.x * WPB + wv;         // 0..2047
    const int pstart   = blockIdx.x & (NPAIR - 1);      // stagger the sweep

    // Stage pair p (16 KB = tiles 2p,2p+1) into bsm[buf]: 16 chunks of 1 KB,
    // 4 per wave, each one global_load_lds (64 lanes x 16 B, linear dst).
    auto stage = [&](int buf, int p) {
        const uint8_t* src = eimg + ((size_t)p << 14) + (size_t)(wv * 4) * 1024 + (size_t)lane * 16;
        uint8_t* dst = &bsm[buf][(wv * 4) * 1024];
        #pragma unroll
        for (int c = 0; c < 4; ++c)
            __builtin_amdgcn_global_load_lds(
                (const __attribute__((address_space(1))) uint32_t*)(src + c * 1024),
                (__attribute__((address_space(3))) uint32_t*)(dst + c * 1024), 16, 0, 0);
    };

    // Prologue: stage pairs 0 and 1; their latency hides under the A-prep.
    stage(0, pstart);
    stage(1, (pstart + 1) & (NPAIR - 1));

    // ---- A fragments: fp8(x), 32 rows/wave = 32 VGPRs (r0-proven 8-deep
    // load batches). ----
    i64x4 A[NRS][2];
    float ss = 0.f;
    #pragma unroll
    for (int rs = 0; rs < NRS; ++rs) {
        const float* xrow = x + (size_t)(waverow + rs*16 + l16) * DIM + quad*32;
        #pragma unroll
        for (int kb = 0; kb < 2; ++kb) {
            const float4* p = (const float4*)(xrow + kb*128);
            float4 v0=p[0],v1=p[1],v2=p[2],v3=p[3],v4=p[4],v5=p[5],v6=p[6],v7=p[7];
            ss += v0.x*v0.x+v0.y*v0.y+v0.z*v0.z+v0.w*v0.w
                + v1.x*v1.x+v1.y*v1.y+v1.z*v1.z+v1.w*v1.w
                + v2.x*v2.x+v2.y*v2.y+v2.z*v2.z+v2.w*v2.w
                + v3.x*v3.x+v3.y*v3.y+v3.z*v3.z+v3.w*v3.w
                + v4.x*v4.x+v4.y*v4.y+v4.z*v4.z+v4.w*v4.w
                + v5.x*v5.x+v5.y*v5.y+v5.z*v5.z+v5.w*v5.w
                + v6.x*v6.x+v6.y*v6.y+v6.z*v6.z+v6.w*v6.w
                + v7.x*v7.x+v7.y*v7.y+v7.z*v7.z+v7.w*v7.w;
            i64x4 a;
            a.x = pk8(v0, v1); a.y = pk8(v2, v3);
            a.z = pk8(v4, v5); a.w = pk8(v6, v7);
            A[rs][kb] = a;
        }
    }
    // ss: full-wave sum of x^2 over this wave's 32 rows -> lane 0.
    #pragma unroll
    for (int off = 32; off; off >>= 1) ss += __shfl_down(ss, off);

    float rmin[NRS][4];
    #pragma unroll
    for (int rs = 0; rs < NRS; ++rs)
        #pragma unroll
        for (int r = 0; r < 4; ++r) rmin[rs][r] = 3.402823466e+38f;

    union BU { i32x8 v; i64x4 q; struct { int4 lo, hi; } s; };

    // Full MFMA + pack/min work for one 32-col tile; `half` selects the 8 KB
    // half of the 16 KB pair buffer, ctv is the GLOBAL tile index (colbase).
    auto computeT = [&](int buf, int half, int ctv) {
        const uint8_t* base = &bsm[buf][half * 8192] + (size_t)lane * 16;
        BU b[2][2];
        #pragma unroll
        for (int sub = 0; sub < 2; ++sub)
            #pragma unroll
            for (int kb = 0; kb < 2; ++kb) {
                const uint8_t* pB = base + (sub*2 + kb) * 2048;
                b[sub][kb].s.lo = *(const int4*)pB;
                b[sub][kb].s.hi = *(const int4*)(pB + 1024);
            }
        const int colbase = ctv * CTILE;
        #pragma unroll
        for (int sub = 0; sub < 2; ++sub) {
            f32x4 acc[NRS];
            #pragma unroll
            for (int rs = 0; rs < NRS; ++rs) acc[rs] = (f32x4){0.f,0.f,0.f,0.f};
            __builtin_amdgcn_s_setprio(1);          // T5: favor MFMA-feeding wave
            #pragma unroll
            for (int kb = 0; kb < 2; ++kb) {
#ifdef HAVE_MXFMA
                #pragma unroll
                for (int rs = 0; rs < NRS; ++rs)
                    acc[rs] = __builtin_amdgcn_mfma_scale_f32_16x16x128_f8f6f4(
                        __builtin_bit_cast(i32x8, A[rs][kb]), b[sub][kb].v, acc[rs],
                        0, 0, 0, 0x7F7F7F7F, 0, 0x7F7F7F7F);
#else
                #pragma unroll
                for (int rs = 0; rs < NRS; ++rs) {
                    acc[rs] = __builtin_amdgcn_mfma_f32_16x16x32_fp8_fp8(A[rs][kb].x, b[sub][kb].q.x, acc[rs], 0, 0, 0);
                    acc[rs] = __builtin_amdgcn_mfma_f32_16x16x32_fp8_fp8(A[rs][kb].y, b[sub][kb].q.y, acc[rs], 0, 0, 0);
                    acc[rs] = __builtin_amdgcn_mfma_f32_16x16x32_fp8_fp8(A[rs][kb].z, b[sub][kb].q.z, acc[rs], 0, 0, 0);
                    acc[rs] = __builtin_amdgcn_mfma_f32_16x16x32_fp8_fp8(A[rs][kb].w, b[sub][kb].q.w, acc[rs], 0, 0, 0);
                }
#endif
            }
            __builtin_amdgcn_s_setprio(0);
            const unsigned colv = (unsigned)(colbase + sub*16 + l16);
            // C layout: row = quad*4 + r, col = l16. idx packed in low 12 mantissa
            // bits -> one v_and_or + one v_min_f32 carries (score, idx).
            #pragma unroll
            for (int rs = 0; rs < NRS; ++rs)
                #pragma unroll
                for (int r = 0; r < 4; ++r) {
                    unsigned pk = (__float_as_uint(acc[rs][r]) & 0xFFFFF000u) | colv;
                    rmin[rs][r] = fminf(rmin[rs][r], __uint_as_float(pk));
                }
        }
    };

    __syncthreads();            // prologue: pairs 0,1 staged (full drain, once)

    #pragma unroll 1
    for (int t = 0; t < NPAIR; ++t) {
        if (t + 2 < NPAIR) stage((t + 2) % 3, (pstart + t + 2) & (NPAIR - 1));
        const int p = (pstart + t) & (NPAIR - 1);
        computeT(t % 3, 0, 2 * p);
        computeT(t % 3, 1, 2 * p + 1);
        // Counted wait: pair t+1's DMAs (issued at t-1) must have landed;
        // pair t+2's 4 loads stay in flight across the raw barrier.
        if (t + 2 < NPAIR) {
            asm volatile("s_waitcnt vmcnt(4)" ::: "memory");
        } else {
            asm volatile("s_waitcnt vmcnt(0)" ::: "memory");
        }
        __builtin_amdgcn_s_barrier();
    }

    // ---- Winners: 16-lane reduce, record idx + loss contribution ----
    float lsum = 0.f;
    #pragma unroll
    for (int rs = 0; rs < NRS; ++rs) {
        #pragma unroll
        for (int r = 0; r < 4; ++r) {
            float v = rmin[rs][r];
            v = fminf(v, __shfl_xor(v, 8));
            v = fminf(v, __shfl_xor(v, 4));
            v = fminf(v, __shfl_xor(v, 2));
            v = fminf(v, __shfl_xor(v, 1));
            if (l16 == 0) {
                unsigned u = __float_as_uint(v);
                int idx = (int)(u & 0xFFFu);
                idx_lds[wv*RPW + rs*16 + quad*4 + r] = idx;
                lsum += __uint_as_float(u & 0xFFFFF000u) * (1.0f / SSCALE) + e2s[idx];
            }
        }
    }
    // lsum lives in lanes 0,16,32,48 -> lane 0; combine with ss.
    lsum += __shfl_down(lsum, 32);
    lsum += __shfl_down(lsum, 16);
    if (lane == 0) parts[wgrp] = ss + lsum;

    __syncthreads();                    // idx_lds visible to all waves

    // ---- Gather emb[idx] -> out: 128 rows x 64 float4, 32 per thread.
    // Each wave handles one row per iter: uniform idx -> coalesced 1 KB read
    // from L2-resident emb, coalesced 1 KB write to out.
    #pragma unroll 4
    for (int it = 0; it < 32; ++it) {
        int fi  = it * 256 + tid;
        int row = fi >> 6;
        int c4  = fi & 63;
        float4 q = ((const float4*)(emb + (size_t)idx_lds[row] * DIM))[c4];
        ((float4*)(out + (size_t)(rowblock + row) * DIM))[c4] = q;
    }
}

// K3: loss = 1.25/Nel * sum parts[2048]
__global__ void vq_loss(const float* __restrict__ parts,
                        float* __restrict__ loss_slot) {
    __shared__ float wsum[4];
    const int tid = threadIdx.x;
    float s = 0.f;
    #pragma unroll
    for (int i = 0; i < WGRPS/256; ++i) s += parts[i * 256 + tid];
    #pragma unroll
    for (int off = 32; off; off >>= 1) s += __shfl_down(s, off);
    if ((tid & 63) == 0) wsum[tid >> 6] = s;
    __syncthreads();
    if (tid == 0)
        loss_slot[0] = (wsum[0] + wsum[1] + wsum[2] + wsum[3]) * (1.25f / 16777216.f);
}

extern "C" void kernel_launch(void* const* d_in, const int* in_sizes, int n_in,
                              void* d_out, int out_size, void* d_ws, size_t ws_size,
                              hipStream_t stream) {
    const float* x   = (const float*)d_in[0];   // [32,2048,256]
    const float* emb = (const float*)d_in[1];   // [4096,256]
    float* out = (float*)d_out;                 // 16777216 quantised_st + 1 loss

    uint8_t* eimg = (uint8_t*)d_ws;                                    // 1 MB
    float* e2s    = (float*)((char*)d_ws + (size_t)VOCAB*DIM);         // 16 KB
    float* parts  = (float*)((char*)e2s + VOCAB*4);                    // 8 KB
    float* loss_slot = out + (size_t)NROWS * DIM;

    vq_prep<<<VOCAB/CTILE, 256, 0, stream>>>(emb, eimg, e2s);
    vq_argmin<<<NBLK, 64*WPB, 0, stream>>>(x, eimg, e2s, emb, out, parts);
    vq_loss<<<1, 256, 0, stream>>>(parts, loss_slot);
}